// Round 12
// baseline (506.526 us; speedup 1.0000x reference)
//
#include <hip/hip_runtime.h>
#include <math.h>

#define NROW 16384   // B*N rows
#define NCOL 4096
#define CDIM 256
#define DKDIM 64
#define SCALE 0.125f // DK^-0.5

typedef float v4f __attribute__((ext_vector_type(4)));
typedef __attribute__((ext_vector_type(8))) short short8v;  // 8 bf16 = 4 VGPR
typedef __attribute__((ext_vector_type(4))) float f32x4;

// ---- monotone float<->u32 key helpers (unsigned compare == float compare) ----
__device__ __forceinline__ unsigned mono(float v) {
  unsigned u = __float_as_uint(v);
  unsigned s = (unsigned)(((int)u) >> 31);
  return u ^ (s | 0x80000000u);
}
__device__ __forceinline__ float unmono(unsigned k) {
  unsigned u = (k & 0x80000000u) ? (k ^ 0x80000000u) : ~k;
  return __uint_as_float(u);
}
__device__ __forceinline__ unsigned short f2bf(float f) {  // RNE bf16
  unsigned u = __float_as_uint(f);
  u += 0x7FFFu + ((u >> 16) & 1u);
  return (unsigned short)(u >> 16);
}
__device__ __forceinline__ unsigned umaxu(unsigned a, unsigned b) { return a > b ? a : b; }

// ---- top-8 maintenance on packed keys (proven group-of-8 insert logic) ----
__device__ __forceinline__ void ins8(unsigned tk[8], unsigned& tmin, int& tmpos, unsigned v) {
  #pragma unroll
  for (int j = 0; j < 8; ++j) if (j == tmpos) tk[j] = v;
  tmin = tk[0]; tmpos = 0;
  #pragma unroll
  for (int j = 1; j < 8; ++j) if (tk[j] < tmin) { tmin = tk[j]; tmpos = j; }
}
__device__ __forceinline__ unsigned umax8(const unsigned kv[8]) {
  unsigned a = umaxu(umaxu(kv[0], kv[1]), umaxu(kv[2], kv[3]));
  unsigned b = umaxu(umaxu(kv[4], kv[5]), umaxu(kv[6], kv[7]));
  return umaxu(a, b);
}
__device__ __forceinline__ void seed8r(const unsigned kv[8],
                                       unsigned tk[8], unsigned& tmin, int& tmpos) {
  #pragma unroll
  for (int j = 0; j < 8; ++j) tk[j] = kv[j];
  tmin = tk[0]; tmpos = 0;
  #pragma unroll
  for (int j = 1; j < 8; ++j) if (tk[j] < tmin) { tmin = tk[j]; tmpos = j; }
}
__device__ __forceinline__ void scan8r(const unsigned kvin[8],
                                       unsigned tk[8], unsigned& tmin, int& tmpos) {
  unsigned kv[8];
  #pragma unroll
  for (int j = 0; j < 8; ++j) kv[j] = kvin[j];
  unsigned gm = umax8(kv);
  #pragma unroll
  for (int pass = 0; pass < 2; ++pass) {
    if (__any(gm > tmin)) {            // wave-uniform branch
      if (gm > tmin) {                 // per-lane insert (keys unique by oct id)
        ins8(tk, tmin, tmpos, gm);
        #pragma unroll
        for (int j = 0; j < 8; ++j) if (kv[j] == gm) kv[j] = 0u;
      }
      gm = umax8(kv);
    }
  }
  if (__any(gm > tmin)) {              // rare: >=3 qualifiers in this group
    #pragma unroll
    for (int j = 0; j < 8; ++j) if (kv[j] > tmin) ins8(tk, tmin, tmpos, kv[j]);
  }
}

// LDS key array XOR swizzle (u32 granularity, keeps uint4 alignment)
__device__ __forceinline__ int kswz(int row, int off) {
  return row * 512 + (off ^ (((off >> 6) & 7) << 2));
}
__device__ __forceinline__ void ld8swz(const unsigned* k, int row, int off,
                                       unsigned kv[8]) {
  uint4 ka = *(const uint4*)&k[kswz(row, off)];
  uint4 kb = *(const uint4*)&k[kswz(row, off + 4)];
  kv[0] = ka.x; kv[1] = ka.y; kv[2] = ka.z; kv[3] = ka.w;
  kv[4] = kb.x; kv[5] = kb.y; kv[6] = kb.z; kv[7] = kb.w;
}

// ---------------- Kernel 1: fused Q/K projection (fp32 + bf16 row-major) ----
__global__ __launch_bounds__(512, 2) void qk_proj(
    const float* __restrict__ x, const float* __restrict__ Wq,
    const float* __restrict__ Wk, float* __restrict__ Qt,
    float* __restrict__ Kt, unsigned short* __restrict__ Qh,
    unsigned short* __restrict__ Kh) {
  __shared__ float4 xs4[64][65];  // row stride 65 f4-units -> bank-group spread
  const int t = threadIdx.x;
  const int rb = blockIdx.x;      // 256 blocks of 64 rows
  {
    const float4* xg = (const float4*)(x + (size_t)rb * 64 * CDIM);
    #pragma unroll
    for (int i = 0; i < 8; ++i) {
      int idx = i * 512 + t;      // 0..4095
      xs4[idx >> 6][idx & 63] = xg[idx];
    }
  }
  __syncthreads();

  const int lane = t & 63;
  const int wu = __builtin_amdgcn_readfirstlane(t >> 6);  // wave id, uniform
  const int proj = wu >> 2;
  const int chunk = wu & 3;       // d-chunk: d = chunk*16 .. +15
  const float* __restrict__ Wp = proj ? Wk : Wq;

  float acc[16];
  #pragma unroll
  for (int j = 0; j < 16; ++j) acc[j] = 0.f;

  #pragma unroll 4
  for (int cs = 0; cs < 64; ++cs) {        // 4 c's per step
    float4 xv = xs4[lane][cs];
    const float xc[4] = {xv.x, xv.y, xv.z, xv.w};
    #pragma unroll
    for (int i = 0; i < 4; ++i) {
      const float4* __restrict__ w4 =
          (const float4*)(Wp + (size_t)(cs * 4 + i) * DKDIM + chunk * 16);
      float4 wa = w4[0], wb = w4[1], wc = w4[2], wd = w4[3];
      float xi = xc[i];
      acc[0]  = fmaf(xi, wa.x, acc[0]);  acc[1]  = fmaf(xi, wa.y, acc[1]);
      acc[2]  = fmaf(xi, wa.z, acc[2]);  acc[3]  = fmaf(xi, wa.w, acc[3]);
      acc[4]  = fmaf(xi, wb.x, acc[4]);  acc[5]  = fmaf(xi, wb.y, acc[5]);
      acc[6]  = fmaf(xi, wb.z, acc[6]);  acc[7]  = fmaf(xi, wb.w, acc[7]);
      acc[8]  = fmaf(xi, wc.x, acc[8]);  acc[9]  = fmaf(xi, wc.y, acc[9]);
      acc[10] = fmaf(xi, wc.z, acc[10]); acc[11] = fmaf(xi, wc.w, acc[11]);
      acc[12] = fmaf(xi, wd.x, acc[12]); acc[13] = fmaf(xi, wd.y, acc[13]);
      acc[14] = fmaf(xi, wd.z, acc[14]); acc[15] = fmaf(xi, wd.w, acc[15]);
    }
  }

  const int gr = rb * 64 + lane;  // global row
  float* Of = (proj ? Kt : Qt) + (size_t)gr * 64 + chunk * 16;
  #pragma unroll
  for (int i = 0; i < 4; ++i) {
    float4 o = {acc[4 * i], acc[4 * i + 1], acc[4 * i + 2], acc[4 * i + 3]};
    ((float4*)Of)[i] = o;
  }
  unsigned short* Oh = (proj ? Kh : Qh) + (size_t)gr * 64 + chunk * 16;
  unsigned hp[8];
  #pragma unroll
  for (int i = 0; i < 8; ++i)
    hp[i] = (unsigned)f2bf(acc[2 * i]) | ((unsigned)f2bf(acc[2 * i + 1]) << 16);
  uint4 h0 = {hp[0], hp[1], hp[2], hp[3]};
  uint4 h1 = {hp[4], hp[5], hp[6], hp[7]};
  ((uint4*)Oh)[0] = h0;
  ((uint4*)Oh)[1] = h1;
}

// ---------------- Kernel 2: FUSED oct funnel, 8-wave / 100% occupancy -------
// r4-r11 invariant: s_fused ~185-220 us with ALL pipes at 20-35% across every
// VALU/store/selection variant => latency-bound; occupancy was capped at 16
// waves/CU (50%) the whole time. This round: 512-thread blocks (8 waves),
// grid 1024, LDS unchanged 36 KB -> 4 blocks/CU x 8 waves = 32 waves/CU
// (100%). Per-wave serial work halves (4 oct-groups, 2 phase-3 passes,
// 2 fill rows); same oct math, same spans, same depth-16 funnel, same exact
// fp32 fma order as r9. Fill stays in-kernel (r11: separate fill net-worse).
__global__ __launch_bounds__(512, 8) void s_fused(
    const unsigned short* __restrict__ Qh, const unsigned short* __restrict__ Kh,
    const float* __restrict__ Qt, const float* __restrict__ Kt,
    float* __restrict__ out) {
  __shared__ unsigned keys[16 * 512];   // 32 KB, XOR-swizzled oct-keys
  __shared__ unsigned cand[16][64];     // 4 KB survivors
  float (*pval)[8] = (float(*)[8])keys;          // overlay (keys dead after ph2)
  int   (*pcol)[8] = (int(*)[8])(keys + 128);

  const int t = threadIdx.x;
  const int lane = t & 63;
  const int wu = __builtin_amdgcn_readfirstlane(t >> 6);  // 0..7
  // XCD-chunked bijective swizzle (1024 = 8*128)
  const int bid = blockIdx.x;
  const int orig = (bid & 7) * 128 + (bid >> 3);
  const int blockrow = orig * 16;  // global row base
  const int b = blockrow >> 12;    // batch

  const int l15 = lane & 15, lk = lane >> 4;
  // A-fragments: the block's 16 Q rows. row = lane&15, k = (lane>>4)*8+j.
  const int rowg = blockrow + l15;
  const short8v a0 = *(const short8v*)(Qh + (size_t)rowg * 64 + lk * 8);
  const short8v a1 = *(const short8v*)(Qh + (size_t)rowg * 64 + lk * 8 + 32);
  const unsigned short* Kb = Kh + ((size_t)(b << 12)) * 64;

  // ---- Phase 1: MFMA + oct-max over my 512-col slice (4 oct-groups) ----
  unsigned okey[4][4];             // [stream i][group g]
  #pragma unroll 1
  for (int g = 0; g < 4; ++g) {
    float om[4];
    #pragma unroll
    for (int t8 = 0; t8 < 8; ++t8) {
      const int col = wu * 512 + g * 128 + t8 * 16 + l15;
      const unsigned short* kp = Kb + (size_t)col * 64 + lk * 8;
      const short8v b0 = *(const short8v*)(kp);        // B: col=lane&15, k-half 0
      const short8v b1 = *(const short8v*)(kp + 32);   // k-half 1
      f32x4 acc = {0.f, 0.f, 0.f, 0.f};
      acc = __builtin_amdgcn_mfma_f32_16x16x32_bf16(a0, b0, acc, 0, 0, 0);
      acc = __builtin_amdgcn_mfma_f32_16x16x32_bf16(a1, b1, acc, 0, 0, 0);
      // C/D: col=lane&15, row=(lane>>4)*4+i (m89-verified)
      #pragma unroll
      for (int i = 0; i < 4; ++i)
        om[i] = (t8 == 0) ? acc[i] : fmaxf(om[i], acc[i]);
    }
    const unsigned oid = (unsigned)(((wu * 4 + g) << 4) | l15);  // 9 bits
    #pragma unroll
    for (int i = 0; i < 4; ++i)
      okey[i][g] = (mono(om[i]) & 0xFFFFFE00u) | oid;  // 23 value bits
  }
  #pragma unroll
  for (int i = 0; i < 4; ++i) {    // write 4 oct-keys per stream (one uint4)
    const int row = lk * 4 + i;
    const int off = wu * 64 + l15 * 4;
    uint4 s0 = {okey[i][0], okey[i][1], okey[i][2], okey[i][3]};
    *(uint4*)&keys[kswz(row, off)] = s0;
  }
  __syncthreads();

  // ---- Phase 2: 8 scan-lanes/row, each scans a 64-key span -> 64 surv/row --
  if ((t & 31) < 8) {
    const int row = t >> 5, s = t & 7;   // 16 rows x 8 spans, 128 active lanes
    const int base = s * 64;
    unsigned kv[8]; unsigned mt[8]; unsigned mmin; int mmpos;
    ld8swz(keys, row, base, kv);
    seed8r(kv, mt, mmin, mmpos);
    #pragma unroll
    for (int m = 1; m < 8; ++m) {
      ld8swz(keys, row, base + m * 8, kv);
      scan8r(kv, mt, mmin, mmpos);
    }
    uint4 o0 = {mt[0], mt[1], mt[2], mt[3]};
    uint4 o1 = {mt[4], mt[5], mt[6], mt[7]};
    uint4* cp = (uint4*)(&cand[row][s * 8]);
    cp[0] = o0; cp[1] = o1;
  }
  __syncthreads();

  // ---- Phase 3: top-16 octs -> 128 cols -> exact recompute + softmax ----
  #pragma unroll 1
  for (int p = 0; p < 2; ++p) {
    const int rr = p * 8 + wu;     // my wave's row this pass
    unsigned ok = cand[rr][lane];
    const int q2 = lane >> 2, e2 = lane & 3;  // oct rank / col pair within oct
    unsigned mykey = 0u;
    #pragma unroll
    for (int it = 0; it < 16; ++it) {  // branchless: keys unique -> self-zero
      unsigned m = ok;
      #pragma unroll
      for (int d = 1; d < 64; d <<= 1) m = umaxu(m, (unsigned)__shfl_xor((int)m, d, 64));
      if (q2 == it) mykey = m;         // lane group q2 takes winner #it
      if (ok == m) ok = 0u;
    }
    const unsigned oid = mykey & 0x1FFu;
    const int colb = (int)((oid >> 4) * 128 + (oid & 15u));
    const int col0 = colb + e2 * 16;   // t8 = e2
    const int col1 = col0 + 64;        // t8 = e2 + 4
    const float4* Kp0 = (const float4*)(Kt + ((size_t)((b << 12) + col0)) * 64);
    const float4* Kp1 = (const float4*)(Kt + ((size_t)((b << 12) + col1)) * 64);
    const float4* Qp = (const float4*)(Qt + (size_t)(blockrow + rr) * 64);  // uniform
    float s0 = 0.f, s1 = 0.f;
    #pragma unroll
    for (int g2 = 0; g2 < 16; ++g2) {  // same sequential fma order per column
      float4 qf = Qp[g2];
      float4 k0f = Kp0[g2];
      float4 k1f = Kp1[g2];
      s0 = fmaf(qf.x, k0f.x, s0); s1 = fmaf(qf.x, k1f.x, s1);
      s0 = fmaf(qf.y, k0f.y, s0); s1 = fmaf(qf.y, k1f.y, s1);
      s0 = fmaf(qf.z, k0f.z, s0); s1 = fmaf(qf.z, k1f.z, s1);
      s0 = fmaf(qf.w, k0f.w, s0); s1 = fmaf(qf.w, k1f.w, s1);
    }
    unsigned k0 = mono(s0), k1 = mono(s1);  // full precision: exact ordering
    float vals[8]; int cols[8];
    #pragma unroll
    for (int it = 0; it < 8; ++it) {
      unsigned m = umaxu(k0, k1);
      #pragma unroll
      for (int d = 1; d < 64; d <<= 1) m = umaxu(m, (unsigned)__shfl_xor((int)m, d, 64));
      unsigned long long win = __ballot(k0 == m || k1 == m);
      int wl = (int)__ffsll(win) - 1;
      int mycol = (k0 == m) ? col0 : col1;   // slot resolved on owner lane
      cols[it] = __shfl(mycol, wl, 64);
      vals[it] = unmono(m);
      if (lane == wl) { if (k0 == m) k0 = 0u; else k1 = 0u; }  // exclude winner
    }
    float vq[8]; float sum = 0.f;
    #pragma unroll
    for (int it = 0; it < 8; ++it) { vq[it] = __expf((vals[it] - vals[0]) * SCALE); sum += vq[it]; }
    float inv = 1.f / sum;
    if (lane < 8) {
      pval[rr][lane] = vq[lane] * inv;
      pcol[rr][lane] = cols[lane];
    }
  }
  // no barrier: phase 4 rows {wu, wu+8} were produced by this wave

  // ---- Phase 4a: plain zero-fill of my wave's 2 rows ----
  {
    const v4f z = {0.f, 0.f, 0.f, 0.f};
    #pragma unroll 1
    for (int j = 0; j < 2; ++j) {
      const int sr = wu + 8 * j;
      v4f* orow4 = (v4f*)(out + ((size_t)(blockrow + sr) << 12));
      #pragma unroll
      for (int i = 0; i < 16; ++i)
        orow4[(size_t)i * 64 + lane] = z;
    }
  }
  // drain fill stores (per-wave) so the sparse patch lands after them
  asm volatile("s_waitcnt vmcnt(0)" ::: "memory");
  // ---- Phase 4b: sparse patch by the same wave that filled the rows ----
  if (lane < 16) {
    const int sr = wu + 8 * (lane >> 3);
    const int q = lane & 7;
    out[((size_t)(blockrow + sr) << 12) + (size_t)pcol[sr][q]] = pval[sr][q];
  }
}

extern "C" void kernel_launch(void* const* d_in, const int* in_sizes, int n_in,
                              void* d_out, int out_size, void* d_ws, size_t ws_size,
                              hipStream_t stream) {
  const float* x  = (const float*)d_in[0];
  const float* Wq = (const float*)d_in[1];
  const float* Wk = (const float*)d_in[2];
  float* out = (float*)d_out;

  char* ws = (char*)d_ws;                       // 12 MB used
  float* Qt = (float*)ws;                       // 4 MB fp32 [row][64]
  float* Kt = (float*)(ws + ((size_t)4 << 20)); // 4 MB
  unsigned short* Qh = (unsigned short*)(ws + ((size_t)8 << 20));   // 2 MB bf16
  unsigned short* Kh = (unsigned short*)(ws + ((size_t)10 << 20));  // 2 MB

  qk_proj<<<dim3(NROW / 64), 512, 0, stream>>>(x, Wq, Wk, Qt, Kt, Qh, Kh);
  s_fused<<<1024, 512, 0, stream>>>(Qh, Kh, Qt, Kt, out);
}

// Round 13
// 448.948 us; speedup vs baseline: 1.1283x; 1.1283x over previous
//
#include <hip/hip_runtime.h>
#include <math.h>

#define NROW 16384   // B*N rows
#define NCOL 4096
#define CDIM 256
#define DKDIM 64
#define SCALE 0.125f // DK^-0.5

typedef float v4f __attribute__((ext_vector_type(4)));
typedef __attribute__((ext_vector_type(8))) short short8v;  // 8 bf16 = 4 VGPR
typedef __attribute__((ext_vector_type(4))) float f32x4;

// ---- monotone float<->u32 key helpers (unsigned compare == float compare) ----
__device__ __forceinline__ unsigned mono(float v) {
  unsigned u = __float_as_uint(v);
  unsigned s = (unsigned)(((int)u) >> 31);
  return u ^ (s | 0x80000000u);
}
__device__ __forceinline__ float unmono(unsigned k) {
  unsigned u = (k & 0x80000000u) ? (k ^ 0x80000000u) : ~k;
  return __uint_as_float(u);
}
__device__ __forceinline__ unsigned short f2bf(float f) {  // RNE bf16
  unsigned u = __float_as_uint(f);
  u += 0x7FFFu + ((u >> 16) & 1u);
  return (unsigned short)(u >> 16);
}
__device__ __forceinline__ unsigned umaxu(unsigned a, unsigned b) { return a > b ? a : b; }

// ---- top-8 maintenance on packed keys (proven group-of-8 insert logic) ----
__device__ __forceinline__ void ins8(unsigned tk[8], unsigned& tmin, int& tmpos, unsigned v) {
  #pragma unroll
  for (int j = 0; j < 8; ++j) if (j == tmpos) tk[j] = v;
  tmin = tk[0]; tmpos = 0;
  #pragma unroll
  for (int j = 1; j < 8; ++j) if (tk[j] < tmin) { tmin = tk[j]; tmpos = j; }
}
__device__ __forceinline__ unsigned umax8(const unsigned kv[8]) {
  unsigned a = umaxu(umaxu(kv[0], kv[1]), umaxu(kv[2], kv[3]));
  unsigned b = umaxu(umaxu(kv[4], kv[5]), umaxu(kv[6], kv[7]));
  return umaxu(a, b);
}
__device__ __forceinline__ void seed8r(const unsigned kv[8],
                                       unsigned tk[8], unsigned& tmin, int& tmpos) {
  #pragma unroll
  for (int j = 0; j < 8; ++j) tk[j] = kv[j];
  tmin = tk[0]; tmpos = 0;
  #pragma unroll
  for (int j = 1; j < 8; ++j) if (tk[j] < tmin) { tmin = tk[j]; tmpos = j; }
}
__device__ __forceinline__ void scan8r(const unsigned kvin[8],
                                       unsigned tk[8], unsigned& tmin, int& tmpos) {
  unsigned kv[8];
  #pragma unroll
  for (int j = 0; j < 8; ++j) kv[j] = kvin[j];
  unsigned gm = umax8(kv);
  #pragma unroll
  for (int pass = 0; pass < 2; ++pass) {
    if (__any(gm > tmin)) {            // wave-uniform branch
      if (gm > tmin) {                 // per-lane insert (keys unique: col in low bits)
        ins8(tk, tmin, tmpos, gm);
        #pragma unroll
        for (int j = 0; j < 8; ++j) if (kv[j] == gm) kv[j] = 0u;
      }
      gm = umax8(kv);
    }
  }
  if (__any(gm > tmin)) {              // rare: >=3 qualifiers in this group
    #pragma unroll
    for (int j = 0; j < 8; ++j) if (kv[j] > tmin) ins8(tk, tmin, tmpos, kv[j]);
  }
}
__device__ __forceinline__ void seed8(const unsigned* __restrict__ sp,
                                      unsigned tk[8], unsigned& tmin, int& tmpos) {
  uint4 ka = *(const uint4*)(sp);
  uint4 kb = *(const uint4*)(sp + 4);
  unsigned kv[8] = {ka.x, ka.y, ka.z, ka.w, kb.x, kb.y, kb.z, kb.w};
  seed8r(kv, tk, tmin, tmpos);
}
__device__ __forceinline__ void scan8(const unsigned* __restrict__ sp,
                                      unsigned tk[8], unsigned& tmin, int& tmpos) {
  uint4 ka = *(const uint4*)(sp);
  uint4 kb = *(const uint4*)(sp + 4);
  unsigned kv[8] = {ka.x, ka.y, ka.z, ka.w, kb.x, kb.y, kb.z, kb.w};
  scan8r(kv, tk, tmin, tmpos);
}

// ---------------- Kernel 1: fused Q/K projection (fp32 + bf16 row-major) ----
__global__ __launch_bounds__(512, 2) void qk_proj(
    const float* __restrict__ x, const float* __restrict__ Wq,
    const float* __restrict__ Wk, float* __restrict__ Qt,
    float* __restrict__ Kt, unsigned short* __restrict__ Qh,
    unsigned short* __restrict__ Kh) {
  __shared__ float4 xs4[64][65];  // row stride 65 f4-units -> bank-group spread
  const int t = threadIdx.x;
  const int rb = blockIdx.x;      // 256 blocks of 64 rows
  {
    const float4* xg = (const float4*)(x + (size_t)rb * 64 * CDIM);
    #pragma unroll
    for (int i = 0; i < 8; ++i) {
      int idx = i * 512 + t;      // 0..4095
      xs4[idx >> 6][idx & 63] = xg[idx];
    }
  }
  __syncthreads();

  const int lane = t & 63;
  const int wu = __builtin_amdgcn_readfirstlane(t >> 6);  // wave id, uniform
  const int proj = wu >> 2;
  const int chunk = wu & 3;       // d-chunk: d = chunk*16 .. +15
  const float* __restrict__ Wp = proj ? Wk : Wq;

  float acc[16];
  #pragma unroll
  for (int j = 0; j < 16; ++j) acc[j] = 0.f;

  #pragma unroll 4
  for (int cs = 0; cs < 64; ++cs) {        // 4 c's per step
    float4 xv = xs4[lane][cs];
    const float xc[4] = {xv.x, xv.y, xv.z, xv.w};
    #pragma unroll
    for (int i = 0; i < 4; ++i) {
      const float4* __restrict__ w4 =
          (const float4*)(Wp + (size_t)(cs * 4 + i) * DKDIM + chunk * 16);
      float4 wa = w4[0], wb = w4[1], wc = w4[2], wd = w4[3];
      float xi = xc[i];
      acc[0]  = fmaf(xi, wa.x, acc[0]);  acc[1]  = fmaf(xi, wa.y, acc[1]);
      acc[2]  = fmaf(xi, wa.z, acc[2]);  acc[3]  = fmaf(xi, wa.w, acc[3]);
      acc[4]  = fmaf(xi, wb.x, acc[4]);  acc[5]  = fmaf(xi, wb.y, acc[5]);
      acc[6]  = fmaf(xi, wb.z, acc[6]);  acc[7]  = fmaf(xi, wb.w, acc[7]);
      acc[8]  = fmaf(xi, wc.x, acc[8]);  acc[9]  = fmaf(xi, wc.y, acc[9]);
      acc[10] = fmaf(xi, wc.z, acc[10]); acc[11] = fmaf(xi, wc.w, acc[11]);
      acc[12] = fmaf(xi, wd.x, acc[12]); acc[13] = fmaf(xi, wd.y, acc[13]);
      acc[14] = fmaf(xi, wd.z, acc[14]); acc[15] = fmaf(xi, wd.w, acc[15]);
    }
  }

  const int gr = rb * 64 + lane;  // global row
  float* Of = (proj ? Kt : Qt) + (size_t)gr * 64 + chunk * 16;
  #pragma unroll
  for (int i = 0; i < 4; ++i) {
    float4 o = {acc[4 * i], acc[4 * i + 1], acc[4 * i + 2], acc[4 * i + 3]};
    ((float4*)Of)[i] = o;
  }
  unsigned short* Oh = (proj ? Kh : Qh) + (size_t)gr * 64 + chunk * 16;
  unsigned hp[8];
  #pragma unroll
  for (int i = 0; i < 8; ++i)
    hp[i] = (unsigned)f2bf(acc[2 * i]) | ((unsigned)f2bf(acc[2 * i + 1]) << 16);
  uint4 h0 = {hp[0], hp[1], hp[2], hp[3]};
  uint4 h1 = {hp[4], hp[5], hp[6], hp[7]};
  ((uint4*)Oh)[0] = h0;
  ((uint4*)Oh)[1] = h1;
}

// ---------------- Kernel 2: FUSED S + top-k + exact recompute + softmax -----
// Round-4 configuration: best harness-verified total (448.3 us, s_fused 185).
// Block = 32 rows x 4096 cols, 4 waves. Wave (rg,h): rows rg*16..+15, cols
// h*2048..+2047. Phase 1: MFMA tiles + register scan8r -> per-stream top-8 ->
// LDS (256 keys/row). Phase 2: 8 lanes/row scan 32 keys -> 64 candidates/row.
// Phase 3: exact fp32 recompute of 64 candidates (same fma order), shuffle
// top-8 extraction, softmax -> LDS. Phase 4: NT-store pass writing each 16 KB
// row with the 8 values patched via compare-select. Later variants (oct
// funnel r7, plain stores r9, rank-select r10, split fill r11, 8-wave r12)
// all measured neutral-to-worse; this is the measured optimum.
__global__ __launch_bounds__(256, 2) void s_fused(
    const unsigned short* __restrict__ Qh, const unsigned short* __restrict__ Kh,
    const float* __restrict__ Qt, const float* __restrict__ Kt,
    float* __restrict__ out) {
  __shared__ unsigned keys[32 * 260];   // 33280 B (pad 260: bank spread)
  __shared__ unsigned cand[32][64];     // 8192 B
  __shared__ float    pval[32][8];      // 1 KB
  __shared__ int      pcol[32][8];      // 1 KB

  const int t = threadIdx.x;
  const int lane = t & 63;
  const int wu = __builtin_amdgcn_readfirstlane(t >> 6);
  const int rg = wu >> 1;          // row-group: 0 -> rows 0-15, 1 -> 16-31
  const int h = wu & 1;            // col half: h*2048
  // XCD-chunked bijective swizzle (512 = 8*64)
  const int bid = blockIdx.x;
  const int orig = (bid & 7) * 64 + (bid >> 3);
  const int blockrow = orig * 32;  // global row base
  const int b = blockrow >> 12;    // batch

  const int l15 = lane & 15, lk = lane >> 4;
  // A-fragments: my 16 Q rows. row = lane&15, k = (lane>>4)*8+j (+32 for a1).
  const int rowg = blockrow + rg * 16 + l15;
  const short8v a0 = *(const short8v*)(Qh + (size_t)rowg * 64 + lk * 8);
  const short8v a1 = *(const short8v*)(Qh + (size_t)rowg * 64 + lk * 8 + 32);

  const unsigned short* Kb = Kh + ((size_t)(b << 12)) * 64;

  // ---- Phase 1: MFMA + register scan over my 2048 cols ----
  unsigned tk[4][8]; unsigned tmin[4]; int tmpos[4];
  #pragma unroll 1
  for (int g = 0; g < 16; ++g) {   // 16 groups of 8 col-tiles
    unsigned kv[4][8];
    #pragma unroll
    for (int t8 = 0; t8 < 8; ++t8) {
      const int col = h * 2048 + (g * 8 + t8) * 16 + l15;
      const unsigned short* kp = Kb + (size_t)col * 64 + lk * 8;
      const short8v b0 = *(const short8v*)(kp);        // B: col=lane&15, k-half 0
      const short8v b1 = *(const short8v*)(kp + 32);   // k-half 1
      f32x4 acc = {0.f, 0.f, 0.f, 0.f};
      acc = __builtin_amdgcn_mfma_f32_16x16x32_bf16(a0, b0, acc, 0, 0, 0);
      acc = __builtin_amdgcn_mfma_f32_16x16x32_bf16(a1, b1, acc, 0, 0, 0);
      // C/D: col=lane&15, row=(lane>>4)*4+i (m89-verified). Pack to keys.
      #pragma unroll
      for (int i = 0; i < 4; ++i)
        kv[i][t8] = (mono(acc[i]) & 0xFFFFF000u) | (unsigned)col;
    }
    if (g == 0) {
      #pragma unroll
      for (int i = 0; i < 4; ++i) seed8r(kv[i], tk[i], tmin[i], tmpos[i]);
    } else {
      #pragma unroll
      for (int i = 0; i < 4; ++i) scan8r(kv[i], tk[i], tmin[i], tmpos[i]);
    }
  }
  // write per-stream top-8: keys[row][h*128 + l15*8 .. +7], row = rg*16+lk*4+i
  #pragma unroll
  for (int i = 0; i < 4; ++i) {
    unsigned* kr = keys + (rg * 16 + lk * 4 + i) * 260 + h * 128 + l15 * 8;
    uint4 s0 = {tk[i][0], tk[i][1], tk[i][2], tk[i][3]};
    uint4 s1 = {tk[i][4], tk[i][5], tk[i][6], tk[i][7]};
    ((uint4*)kr)[0] = s0; ((uint4*)kr)[1] = s1;
  }
  __syncthreads();

  // ---- Phase 2: 8 lanes/row, each scans 32 keys -> 8 -> 64 candidates/row --
  {
    const int row = t >> 3, q = t & 7;
    const unsigned* sp = keys + row * 260 + q * 32;
    unsigned mt[8]; unsigned mmin; int mmpos;
    seed8(sp, mt, mmin, mmpos);
    scan8(sp + 8, mt, mmin, mmpos);
    scan8(sp + 16, mt, mmin, mmpos);
    scan8(sp + 24, mt, mmin, mmpos);
    uint4 o0 = {mt[0], mt[1], mt[2], mt[3]};
    uint4 o1 = {mt[4], mt[5], mt[6], mt[7]};
    uint4* cp = (uint4*)(&cand[row][q * 8]);
    cp[0] = o0; cp[1] = o1;
  }
  __syncthreads();

  // ---- Phase 3: exact fp32 recompute of 64 candidates, top-8, softmax -----
  #pragma unroll 1
  for (int p = 0; p < 8; ++p) {
    const int rr = p * 4 + wu;     // my wave's row this pass
    const unsigned key = cand[rr][lane];
    const int col = (int)(key & 0xFFFu);
    const float4* Kp = (const float4*)(Kt + ((size_t)((b << 12) + col)) * 64);
    const float4* Qp = (const float4*)(Qt + (size_t)(blockrow + rr) * 64);  // uniform
    float s = 0.f;
    #pragma unroll
    for (int g2 = 0; g2 < 16; ++g2) {
      float4 qf = Qp[g2];
      float4 kf = Kp[g2];
      s = fmaf(qf.x, kf.x, s);
      s = fmaf(qf.y, kf.y, s);
      s = fmaf(qf.z, kf.z, s);
      s = fmaf(qf.w, kf.w, s);
    }
    unsigned kx = mono(s);  // full precision: exact ordering
    float vals[8]; int cols[8];
    #pragma unroll
    for (int it = 0; it < 8; ++it) {
      unsigned m = kx;
      #pragma unroll
      for (int d = 1; d < 64; d <<= 1) m = umaxu(m, (unsigned)__shfl_xor((int)m, d, 64));
      unsigned long long win = __ballot(kx == m);
      int wl = (int)__ffsll(win) - 1;
      cols[it] = __shfl(col, wl, 64);
      vals[it] = unmono(m);
      if (lane == wl) kx = 0u;   // exclude winner
    }
    float vq[8]; float sum = 0.f;
    #pragma unroll
    for (int it = 0; it < 8; ++it) { vq[it] = __expf((vals[it] - vals[0]) * SCALE); sum += vq[it]; }
    float inv = 1.f / sum;
    if (lane < 8) {
      pval[rr][lane] = vq[lane] * inv;
      pcol[rr][lane] = cols[lane];
    }
  }
  __syncthreads();

  // ---- Phase 4: pure NT-store pass (zero-fill + patch), 8 rows per wave ----
  #pragma unroll 1
  for (int j = 0; j < 8; ++j) {
    const int sr = wu * 8 + j;     // block-local row
    float vq[8]; int cols[8];
    #pragma unroll
    for (int q2 = 0; q2 < 8; ++q2) { vq[q2] = pval[sr][q2]; cols[q2] = pcol[sr][q2]; }
    v4f* orow4 = (v4f*)(out + ((size_t)(blockrow + sr) << 12));
    #pragma unroll
    for (int i = 0; i < 16; ++i) {
      const int base = i * 256 + lane * 4;
      v4f z = {0.f, 0.f, 0.f, 0.f};
      #pragma unroll
      for (int q2 = 0; q2 < 8; ++q2) {
        z.x = (cols[q2] == base)     ? vq[q2] : z.x;
        z.y = (cols[q2] == base + 1) ? vq[q2] : z.y;
        z.z = (cols[q2] == base + 2) ? vq[q2] : z.z;
        z.w = (cols[q2] == base + 3) ? vq[q2] : z.w;
      }
      __builtin_nontemporal_store(z, &orow4[(size_t)i * 64 + lane]);
    }
  }
}

extern "C" void kernel_launch(void* const* d_in, const int* in_sizes, int n_in,
                              void* d_out, int out_size, void* d_ws, size_t ws_size,
                              hipStream_t stream) {
  const float* x  = (const float*)d_in[0];
  const float* Wq = (const float*)d_in[1];
  const float* Wk = (const float*)d_in[2];
  float* out = (float*)d_out;

  char* ws = (char*)d_ws;                       // 12 MB used
  float* Qt = (float*)ws;                       // 4 MB fp32 [row][64]
  float* Kt = (float*)(ws + ((size_t)4 << 20)); // 4 MB
  unsigned short* Qh = (unsigned short*)(ws + ((size_t)8 << 20));   // 2 MB bf16
  unsigned short* Kh = (unsigned short*)(ws + ((size_t)10 << 20));  // 2 MB

  qk_proj<<<dim3(NROW / 64), 512, 0, stream>>>(x, Wq, Wk, Qt, Kt, Qh, Kh);
  s_fused<<<512, 256, 0, stream>>>(Qh, Kh, Qt, Kt, out);
}